// Round 8
// baseline (459.064 us; speedup 1.0000x reference)
//
#include <hip/hip_runtime.h>
#include <stdint.h>

typedef __bf16 bf16;
typedef __bf16 bf16x8 __attribute__((ext_vector_type(8)));
typedef float floatx4 __attribute__((ext_vector_type(4)));

#define S_LEN 2048
#define DM 1024
#define NH 16
#define DK 64
#define MTOT 4096  // B*S

__device__ __forceinline__ bf16x8 cvt8(float4 lo, float4 hi) {
  bf16x8 a;
  a[0] = (bf16)lo.x; a[1] = (bf16)lo.y; a[2] = (bf16)lo.z; a[3] = (bf16)lo.w;
  a[4] = (bf16)hi.x; a[5] = (bf16)hi.y; a[6] = (bf16)hi.z; a[7] = (bf16)hi.w;
  return a;
}

// ---------------------------------------------------------------------------
// Weight fp32 -> bf16 convert (Wq, Wk, Wv only; reused 32x each).
// ---------------------------------------------------------------------------
__global__ __launch_bounds__(256) void cvt_w_kernel(
    const float* __restrict__ Wq, const float* __restrict__ Wk, const float* __restrict__ Wv,
    bf16* __restrict__ wqb, bf16* __restrict__ wkb, bf16* __restrict__ wvb)
{
  const int z = blockIdx.y;
  const float* src = (z == 0) ? Wq : (z == 1) ? Wk : Wv;
  bf16* dst = (z == 0) ? wqb : (z == 1) ? wkb : wvb;
  const int base = (blockIdx.x * 256 + threadIdx.x) * 8;
  float4 a = *(const float4*)(src + base);
  float4 b = *(const float4*)(src + base + 4);
  *(bf16x8*)(dst + base) = cvt8(a, b);
}

// ---------------------------------------------------------------------------
// Projection GEMM, barrier-free: Y[m,n] = sum_k X[m,k]*W[n,k] + bias[n].
// 128x128 tile, 4 waves 2x2, BK=64. A = X fp32 direct-to-frag (cvt in regs),
// B = W bf16 direct-to-frag. NO LDS, NO __syncthreads: fragments are 16B
// k-contiguous runs; 16 lanes x 64B cover whole cachelines; compiler
// pipelines loads across iterations, 12 waves/CU free-run.
// z: 0=Q(*0.125)->qb [b,h,s,d]  1=K->kb  2=V->vtb [b,h,d,s]
// ---------------------------------------------------------------------------
__global__ __launch_bounds__(256) void proj_kernel(
    const float* __restrict__ Xq, const float* __restrict__ Xk, const float* __restrict__ Xv,
    const bf16* __restrict__ wqb, const bf16* __restrict__ wkb, const bf16* __restrict__ wvb,
    const float* __restrict__ bqp, const float* __restrict__ bkp, const float* __restrict__ bvp,
    bf16* __restrict__ qb, bf16* __restrict__ kb, bf16* __restrict__ vtb)
{
  const int z = blockIdx.z;
  const float* X    = (z == 0) ? Xq  : (z == 1) ? Xk  : Xv;
  const bf16* W     = (z == 0) ? wqb : (z == 1) ? wkb : wvb;
  const float* bias = (z == 0) ? bqp : (z == 1) ? bkp : bvp;

  const int m0 = blockIdx.x * 128;
  const int n0 = blockIdx.y * 128;
  const int tid = threadIdx.x;
  const int lane = tid & 63;
  const int wid = tid >> 6;
  const int wm = (wid & 1) * 64;
  const int wn = (wid >> 1) * 64;

  const int mr = lane & 15;
  const int q4 = lane >> 4;

  floatx4 acc[4][4];
  #pragma unroll
  for (int i = 0; i < 4; i++)
    #pragma unroll
    for (int j = 0; j < 4; j++) acc[i][j] = (floatx4){0.f, 0.f, 0.f, 0.f};

  const float* xbase = X + (size_t)(m0 + wm + mr) * DM;   // + mt*16*DM + k
  const bf16*  wbase = W + (size_t)(n0 + wn + mr) * DM;   // + nt*16*DM + k

  for (int kt = 0; kt < DM; kt += 64) {
    #pragma unroll
    for (int kk = 0; kk < 2; kk++) {
      const int ko = kt + kk * 32 + q4 * 8;
      bf16x8 af[4], bfr[4];
      #pragma unroll
      for (int mt = 0; mt < 4; mt++) {
        const float* p = xbase + (size_t)mt * 16 * DM + ko;
        af[mt] = cvt8(*(const float4*)p, *(const float4*)(p + 4));
      }
      #pragma unroll
      for (int nt = 0; nt < 4; nt++)
        bfr[nt] = *(const bf16x8*)(wbase + (size_t)nt * 16 * DM + ko);
      #pragma unroll
      for (int mt = 0; mt < 4; mt++)
        #pragma unroll
        for (int nt = 0; nt < 4; nt++)
          acc[mt][nt] = __builtin_amdgcn_mfma_f32_16x16x32_bf16(af[mt], bfr[nt], acc[mt][nt], 0, 0, 0);
    }
  }

  const float qscale = (z == 0) ? 0.125f : 1.0f;   // fold 1/sqrt(Dk) into q
  #pragma unroll
  for (int nt = 0; nt < 4; nt++) {
    const int gn = n0 + wn + nt * 16 + mr;
    const float bv = bias[gn];
    const int h = gn >> 6, d = gn & 63;
    #pragma unroll
    for (int mt = 0; mt < 4; mt++) {
      const int mbase = m0 + wm + mt * 16 + q4 * 4;
      #pragma unroll
      for (int r = 0; r < 4; r++) {
        const int gm = mbase + r;
        const int bi = gm >> 11, s = gm & 2047;
        const bf16 hv = (bf16)((acc[mt][nt][r] + bv) * qscale);
        if (z == 2) {
          vtb[(((size_t)(bi * NH + h)) * DK + d) * S_LEN + s] = hv;
        } else if (z == 0) {
          qb[(((size_t)(bi * NH + h)) * S_LEN + s) * DK + d] = hv;
        } else {
          kb[(((size_t)(bi * NH + h)) * S_LEN + s) * DK + d] = hv;
        }
      }
    }
  }
}

// ---------------------------------------------------------------------------
// Flash attention, no-max softmax, barrier-free. K/V fragments loaded
// directly global->VGPR (per-head KV = 512KB, L2-resident). Only LDS use is
// the wave-private P transpose (C-layout -> A-layout), no __syncthreads.
// grid (16 q-tiles, 32 b*h); wave owns 32 q-rows; 16 iters x 128 keys.
// ---------------------------------------------------------------------------
__global__ __launch_bounds__(256) void attn_kernel(
    const bf16* __restrict__ qb, const bf16* __restrict__ kb,
    const bf16* __restrict__ vtb, bf16* __restrict__ ob)
{
  const int qt = blockIdx.x;   // 0..15
  const int bh = blockIdx.y;   // 0..31
  const int tid = threadIdx.x;
  const int lane = tid & 63;
  const int wid = tid >> 6;

  const bf16* qh = qb + (size_t)bh * S_LEN * DK;
  const bf16* kh = kb + (size_t)bh * S_LEN * DK;
  const bf16* vh = vtb + (size_t)bh * DK * S_LEN;

  __shared__ bf16 Ps[4][32][136];   // per-wave P tile

  const int mr = lane & 15;
  const int q4 = lane >> 4;

  bf16x8 aq[2][2];
  #pragma unroll
  for (int mt = 0; mt < 2; mt++)
    #pragma unroll
    for (int kk = 0; kk < 2; kk++)
      aq[mt][kk] = *(const bf16x8*)(qh + (size_t)(qt * 128 + wid * 32 + mt * 16 + mr) * DK + kk * 32 + q4 * 8);

  floatx4 acc_o[2][4];
  #pragma unroll
  for (int mt = 0; mt < 2; mt++)
    #pragma unroll
    for (int dt = 0; dt < 4; dt++) acc_o[mt][dt] = (floatx4){0.f, 0.f, 0.f, 0.f};
  float l_p[2][4] = {{0.f,0.f,0.f,0.f},{0.f,0.f,0.f,0.f}};

  for (int it = 0; it < S_LEN / 128; it++) {
    const int s0 = it * 128;

    // scores: 32 q-rows x 128 keys; K frags straight from global
    floatx4 sc[2][8];
    #pragma unroll
    for (int mt = 0; mt < 2; mt++)
      #pragma unroll
      for (int i = 0; i < 8; i++) sc[mt][i] = (floatx4){0.f, 0.f, 0.f, 0.f};
    #pragma unroll
    for (int kk = 0; kk < 2; kk++) {
      #pragma unroll
      for (int nt = 0; nt < 8; nt++) {
        bf16x8 b = *(const bf16x8*)(kh + (size_t)(s0 + nt * 16 + mr) * DK + kk * 32 + q4 * 8);
        #pragma unroll
        for (int mt = 0; mt < 2; mt++)
          sc[mt][nt] = __builtin_amdgcn_mfma_f32_16x16x32_bf16(aq[mt][kk], b, sc[mt][nt], 0, 0, 0);
      }
    }

    // P = exp(s); per-lane partial row sums; C-layout -> wave-private LDS
    #pragma unroll
    for (int mt = 0; mt < 2; mt++)
      #pragma unroll
      for (int nt = 0; nt < 8; nt++)
        #pragma unroll
        for (int r = 0; r < 4; r++) {
          const float pv = __expf(sc[mt][nt][r]);
          l_p[mt][r] += pv;
          Ps[wid][mt * 16 + q4 * 4 + r][nt * 16 + mr] = (bf16)pv;
        }

    // O += P * V; V^T frags straight from global (within-wave LDS RAW only)
    #pragma unroll
    for (int kk2 = 0; kk2 < 4; kk2++) {
      bf16x8 ap[2];
      #pragma unroll
      for (int mt = 0; mt < 2; mt++)
        ap[mt] = *(const bf16x8*)&Ps[wid][mt * 16 + mr][kk2 * 32 + q4 * 8];
      #pragma unroll
      for (int dt = 0; dt < 4; dt++) {
        bf16x8 b = *(const bf16x8*)(vh + (size_t)(dt * 16 + mr) * S_LEN + s0 + kk2 * 32 + q4 * 8);
        #pragma unroll
        for (int mt = 0; mt < 2; mt++)
          acc_o[mt][dt] = __builtin_amdgcn_mfma_f32_16x16x32_bf16(ap[mt], b, acc_o[mt][dt], 0, 0, 0);
      }
    }
  }

  const int bi = bh >> 4, h = bh & 15;
  #pragma unroll
  for (int mt = 0; mt < 2; mt++) {
    float inv[4];
    #pragma unroll
    for (int r = 0; r < 4; r++) {
      float v = l_p[mt][r];
      #pragma unroll
      for (int off = 1; off < 16; off <<= 1) v += __shfl_xor(v, off, 16);
      inv[r] = 1.0f / v;
    }
    #pragma unroll
    for (int dt = 0; dt < 4; dt++) {
      const int d = dt * 16 + mr;
      #pragma unroll
      for (int r = 0; r < 4; r++) {
        const int s = qt * 128 + wid * 32 + mt * 16 + q4 * 4 + r;
        ob[((size_t)(bi * S_LEN + s)) * DM + h * DK + d] = (bf16)(acc_o[mt][dt][r] * inv[r]);
      }
    }
  }
}

// ---------------------------------------------------------------------------
// Output projection, barrier-free: out = AO @ Wo^T + bo, fp32 out.
// 128x64 tile, 4 waves 2x2 (wave = 64x32). A = ao bf16 direct-to-frag,
// B = Wo fp32 direct-to-frag (cvt in regs). grid (32,16) = 512 blocks.
// ---------------------------------------------------------------------------
__global__ __launch_bounds__(256) void oproj_kernel(
    const bf16* __restrict__ X, const float* __restrict__ W,
    const float* __restrict__ bias, float* __restrict__ out)
{
  const int m0 = blockIdx.x * 128;
  const int n0 = blockIdx.y * 64;
  const int tid = threadIdx.x;
  const int lane = tid & 63;
  const int wid = tid >> 6;
  const int wm = (wid & 1) * 64;
  const int wn = (wid >> 1) * 32;

  const int mr = lane & 15;
  const int q4 = lane >> 4;

  floatx4 acc[4][2];
  #pragma unroll
  for (int i = 0; i < 4; i++)
    #pragma unroll
    for (int j = 0; j < 2; j++) acc[i][j] = (floatx4){0.f, 0.f, 0.f, 0.f};

  const bf16*  xbase = X + (size_t)(m0 + wm + mr) * DM;
  const float* wbase = W + (size_t)(n0 + wn + mr) * DM;

  for (int kt = 0; kt < DM; kt += 64) {
    #pragma unroll
    for (int kk = 0; kk < 2; kk++) {
      const int ko = kt + kk * 32 + q4 * 8;
      bf16x8 af[4], bfr[2];
      #pragma unroll
      for (int mt = 0; mt < 4; mt++)
        af[mt] = *(const bf16x8*)(xbase + (size_t)mt * 16 * DM + ko);
      #pragma unroll
      for (int nt = 0; nt < 2; nt++) {
        const float* p = wbase + (size_t)nt * 16 * DM + ko;
        bfr[nt] = cvt8(*(const float4*)p, *(const float4*)(p + 4));
      }
      #pragma unroll
      for (int mt = 0; mt < 4; mt++)
        #pragma unroll
        for (int nt = 0; nt < 2; nt++)
          acc[mt][nt] = __builtin_amdgcn_mfma_f32_16x16x32_bf16(af[mt], bfr[nt], acc[mt][nt], 0, 0, 0);
    }
  }

  #pragma unroll
  for (int nt = 0; nt < 2; nt++) {
    const int gn = n0 + wn + nt * 16 + mr;
    const float bv = bias[gn];
    #pragma unroll
    for (int mt = 0; mt < 4; mt++) {
      const int mbase = m0 + wm + mt * 16 + q4 * 4;
      #pragma unroll
      for (int r = 0; r < 4; r++)
        out[(size_t)(mbase + r) * DM + gn] = acc[mt][nt][r] + bv;
    }
  }
}

// ---------------------------------------------------------------------------
extern "C" void kernel_launch(void* const* d_in, const int* in_sizes, int n_in,
                              void* d_out, int out_size, void* d_ws, size_t ws_size,
                              hipStream_t stream) {
  const float* Q  = (const float*)d_in[0];
  const float* K  = (const float*)d_in[1];
  const float* V  = (const float*)d_in[2];
  const float* Wq = (const float*)d_in[3];
  const float* bq = (const float*)d_in[4];
  const float* Wk = (const float*)d_in[5];
  const float* bk = (const float*)d_in[6];
  const float* Wv = (const float*)d_in[7];
  const float* bv = (const float*)d_in[8];
  const float* Wo = (const float*)d_in[9];
  const float* bo = (const float*)d_in[10];
  float* out = (float*)d_out;

  const size_t NE = (size_t)MTOT * DM;      // 4 Mi elems
  bf16* qb  = (bf16*)d_ws;                  // [B,H,S,Dk] (q pre-scaled by 1/8)
  bf16* kb  = qb + NE;
  bf16* vtb = kb + NE;                      // [B,H,Dk,S]
  bf16* ao  = vtb + NE;                     // [B*S, DM] attn out
  // bf16 weights aliased into ao (live only during proj; attn overwrites ao).
  bf16* wqb = ao;
  bf16* wkb = ao + (size_t)DM * DM;
  bf16* wvb = ao + 2 * (size_t)DM * DM;

  cvt_w_kernel<<<dim3(512, 3), 256, 0, stream>>>(Wq, Wk, Wv, wqb, wkb, wvb);
  proj_kernel<<<dim3(32, 8, 3), 256, 0, stream>>>(Q, K, V, wqb, wkb, wvb, bq, bk, bv, qb, kb, vtb);
  attn_kernel<<<dim3(16, 32), 256, 0, stream>>>(qb, kb, vtb, ao);
  oproj_kernel<<<dim3(32, 16), 256, 0, stream>>>(ao, Wo, bo, out);
}

// Round 9
// 257.249 us; speedup vs baseline: 1.7845x; 1.7845x over previous
//
#include <hip/hip_runtime.h>
#include <stdint.h>

typedef __bf16 bf16;
typedef __bf16 bf16x8 __attribute__((ext_vector_type(8)));
typedef float floatx4 __attribute__((ext_vector_type(4)));

#define S_LEN 2048
#define DM 1024
#define NH 16
#define DK 64
#define MTOT 4096  // B*S

// async 16B/lane global->LDS DMA; lane l's 16B lands at ldsbase + l*16.
__device__ __forceinline__ void gll16(const void* g, void* l) {
  __builtin_amdgcn_global_load_lds(
      (const __attribute__((address_space(1))) void*)g,
      (__attribute__((address_space(3))) void*)l, 16, 0, 0);
}

// ---------------------------------------------------------------------------
// fp32 -> bf16 convert: Wq,Wk,Wv (512 chunks each) + Xq,Xk (2048 chunks each).
// ---------------------------------------------------------------------------
__global__ __launch_bounds__(256) void cvt_kernel(
    const float* __restrict__ Wq, const float* __restrict__ Wk, const float* __restrict__ Wv,
    const float* __restrict__ Xq, const float* __restrict__ Xk,
    bf16* __restrict__ wqb, bf16* __restrict__ wkb, bf16* __restrict__ wvb,
    bf16* __restrict__ xqb, bf16* __restrict__ xkb)
{
  const int c = blockIdx.x;
  const float* src; bf16* dst; int off;
  if      (c < 512)  { src = Wq; dst = wqb; off = c; }
  else if (c < 1024) { src = Wk; dst = wkb; off = c - 512; }
  else if (c < 1536) { src = Wv; dst = wvb; off = c - 1024; }
  else if (c < 3584) { src = Xq; dst = xqb; off = c - 1536; }
  else               { src = Xk; dst = xkb; off = c - 3584; }
  const size_t base = (size_t)off * 2048 + threadIdx.x * 8;
  float4 a = *(const float4*)(src + base);
  float4 b = *(const float4*)(src + base + 4);
  bf16x8 h;
  h[0] = (bf16)a.x; h[1] = (bf16)a.y; h[2] = (bf16)a.z; h[3] = (bf16)a.w;
  h[4] = (bf16)b.x; h[5] = (bf16)b.y; h[6] = (bf16)b.z; h[7] = (bf16)b.w;
  *(bf16x8*)(dst + base) = h;
}

// ---------------------------------------------------------------------------
// Projection GEMM: Y[m,n] = sum_k X[m,k]*W[n,k] + bias[n]. 128x128 tile.
// z<2: all-bf16, BK=64. z=2: A fp32, BK=64 (32KB A). Round-6 bodies.
// XCD-aware 1-D grid: bid%8 = XCD owns 4 m-stripes x all n x all z, so
// X-stripes + W stay in that XCD's L2 instead of bouncing through L3.
// ---------------------------------------------------------------------------
__global__ __launch_bounds__(256) void proj_kernel(
    const bf16* __restrict__ xqb, const bf16* __restrict__ xkb, const float* __restrict__ Xv,
    const bf16* __restrict__ wqb, const bf16* __restrict__ wkb, const bf16* __restrict__ wvb,
    const float* __restrict__ bqp, const float* __restrict__ bkp, const float* __restrict__ bvp,
    bf16* __restrict__ qb, bf16* __restrict__ kb, bf16* __restrict__ vtb)
{
  // decode: xcd = bid&7, slot = bid>>3 (0..95); m = xcd*4 + (slot&3),
  // n = (slot>>2)&7, z = slot>>5
  const int bid = blockIdx.x;
  const int xcd = bid & 7;
  const int slot = bid >> 3;
  const int m_blk = xcd * 4 + (slot & 3);
  const int n_blk = (slot >> 2) & 7;
  const int z = slot >> 5;

  const bf16* W     = (z == 0) ? wqb : (z == 1) ? wkb : wvb;
  const float* bias = (z == 0) ? bqp : (z == 1) ? bkp : bvp;

  const int m0 = m_blk * 128;
  const int n0 = n_blk * 128;
  const int tid = threadIdx.x;
  const int lane = tid & 63;
  const int wid = tid >> 6;
  const int wm = (wid & 1) * 64;
  const int wn = (wid >> 1) * 64;

  __shared__ unsigned char smemA[32768];   // z<2: bf16[128][64]; z=2: float[128][64]
  __shared__ bf16 Bs[128 * 64];
  bf16*  As16 = (bf16*)smemA;
  float* Asf  = (float*)smemA;

  floatx4 acc[4][4];
  #pragma unroll
  for (int i = 0; i < 4; i++)
    #pragma unroll
    for (int j = 0; j < 4; j++) acc[i][j] = (floatx4){0.f, 0.f, 0.f, 0.f};

  const int mr = lane & 15;
  const int q4 = lane >> 4;

  const int r8_in = lane >> 3, cb8_ph = lane & 7;     // 8-row chunks (bf16 rows)
  const int r4_in = lane >> 4, cb16_ph = lane & 15;   // 4-row chunks (fp32 rows)

  const bf16* Xb = (z == 0) ? xqb : xkb;

  for (int kt = 0; kt < DM; kt += 64) {
    __syncthreads();
    if (z < 2) {
      #pragma unroll
      for (int j = 0; j < 4; j++) {   // A bf16 16KB: 16 chunks (4/wave)
        const int c = wid * 4 + j;
        const int row = c * 8 + r8_in;
        const int cb = cb8_ph ^ (row & 7);
        gll16(Xb + (size_t)(m0 + row) * DM + kt + cb * 8, &As16[c * 512]);
      }
    } else {
      #pragma unroll
      for (int j = 0; j < 8; j++) {   // A fp32 32KB: 32 chunks (8/wave)
        const int c = wid * 8 + j;
        const int row = c * 4 + r4_in;
        const int cb = cb16_ph ^ (row & 7);
        gll16(Xv + (size_t)(m0 + row) * DM + kt + cb * 4, &Asf[c * 256]);
      }
    }
    #pragma unroll
    for (int j = 0; j < 4; j++) {     // B bf16 16KB: 16 chunks (4/wave)
      const int c = wid * 4 + j;
      const int row = c * 8 + r8_in;
      const int cb = cb8_ph ^ (row & 7);
      gll16(W + (size_t)(n0 + row) * DM + kt + cb * 8, &Bs[c * 512]);
    }
    __syncthreads();

    #pragma unroll
    for (int kk = 0; kk < 2; kk++) {
      bf16x8 af[4], bfr[4];
      #pragma unroll
      for (int mt = 0; mt < 4; mt++) {
        const int row = wm + mt * 16 + mr;
        if (z < 2) {
          const int cb = 4 * kk + q4;
          af[mt] = *(const bf16x8*)&As16[row * 64 + (cb ^ (row & 7)) * 8];
        } else {
          const int cb0 = 8 * kk + 2 * q4;
          const float4 lo = *(const float4*)&Asf[row * 64 + (cb0 ^ (row & 7)) * 4];
          const float4 hi = *(const float4*)&Asf[row * 64 + ((cb0 + 1) ^ (row & 7)) * 4];
          bf16x8 a;
          a[0] = (bf16)lo.x; a[1] = (bf16)lo.y; a[2] = (bf16)lo.z; a[3] = (bf16)lo.w;
          a[4] = (bf16)hi.x; a[5] = (bf16)hi.y; a[6] = (bf16)hi.z; a[7] = (bf16)hi.w;
          af[mt] = a;
        }
      }
      #pragma unroll
      for (int nt = 0; nt < 4; nt++) {
        const int row = wn + nt * 16 + mr;
        const int cb = 4 * kk + q4;
        bfr[nt] = *(const bf16x8*)&Bs[row * 64 + (cb ^ (row & 7)) * 8];
      }
      #pragma unroll
      for (int mt = 0; mt < 4; mt++)
        #pragma unroll
        for (int nt = 0; nt < 4; nt++)
          acc[mt][nt] = __builtin_amdgcn_mfma_f32_16x16x32_bf16(af[mt], bfr[nt], acc[mt][nt], 0, 0, 0);
    }
  }

  const float qscale = (z == 0) ? 0.125f : 1.0f;   // fold 1/sqrt(Dk) into q
  #pragma unroll
  for (int nt = 0; nt < 4; nt++) {
    const int gn = n0 + wn + nt * 16 + mr;
    const float bv = bias[gn];
    const int h = gn >> 6, d = gn & 63;
    #pragma unroll
    for (int mt = 0; mt < 4; mt++) {
      const int mbase = m0 + wm + mt * 16 + q4 * 4;
      #pragma unroll
      for (int r = 0; r < 4; r++) {
        const int gm = mbase + r;
        const int bi = gm >> 11, s = gm & 2047;
        const bf16 hv = (bf16)((acc[mt][nt][r] + bv) * qscale);
        if (z == 2) {
          vtb[(((size_t)(bi * NH + h)) * DK + d) * S_LEN + s] = hv;
        } else if (z == 0) {
          qb[(((size_t)(bi * NH + h)) * S_LEN + s) * DK + d] = hv;
        } else {
          kb[(((size_t)(bi * NH + h)) * S_LEN + s) * DK + d] = hv;
        }
      }
    }
  }
}

// ---------------------------------------------------------------------------
// Flash attention, no-max softmax, q-tile 128 (wave owns 32 q-rows).
// XCD-aware 1-D grid: XCD owns 4 heads x all 16 q-tiles -> that XCD's KV
// working set (4 x 512KB) is L2-resident; KV crosses L3 once per XCD.
// ---------------------------------------------------------------------------
__global__ __launch_bounds__(256) void attn_kernel(
    const bf16* __restrict__ qb, const bf16* __restrict__ kb,
    const bf16* __restrict__ vtb, bf16* __restrict__ ob)
{
  const int bid = blockIdx.x;
  const int xcd = bid & 7;
  const int slot = bid >> 3;          // 0..63
  const int bh = xcd * 4 + (slot & 3);
  const int qt = slot >> 2;           // 0..15

  const int tid = threadIdx.x;
  const int lane = tid & 63;
  const int wid = tid >> 6;

  const bf16* qh = qb + (size_t)bh * S_LEN * DK;
  const bf16* kh = kb + (size_t)bh * S_LEN * DK;
  const bf16* vh = vtb + (size_t)bh * DK * S_LEN;

  __shared__ bf16 Ks[128 * 64];     // [key][8 cb], phys cb = cb^(row&7)
  __shared__ bf16 Vs[64 * 128];     // [d][16 cb],  phys cb = cb^(row&7)
  __shared__ bf16 Ps[4][32][136];   // per-wave P tile (C-layout -> A-layout)

  const int mr = lane & 15;
  const int q4 = lane >> 4;

  bf16x8 aq[2][2];
  #pragma unroll
  for (int mt = 0; mt < 2; mt++)
    #pragma unroll
    for (int kk = 0; kk < 2; kk++)
      aq[mt][kk] = *(const bf16x8*)(qh + (size_t)(qt * 128 + wid * 32 + mt * 16 + mr) * DK + kk * 32 + q4 * 8);

  floatx4 acc_o[2][4];
  #pragma unroll
  for (int mt = 0; mt < 2; mt++)
    #pragma unroll
    for (int dt = 0; dt < 4; dt++) acc_o[mt][dt] = (floatx4){0.f, 0.f, 0.f, 0.f};
  float l_p[2][4] = {{0.f,0.f,0.f,0.f},{0.f,0.f,0.f,0.f}};

  const int r8_in = lane >> 3, cb8_ph = lane & 7;
  const int r4_in = lane >> 4, cb16_ph = lane & 15;

  for (int it = 0; it < S_LEN / 128; it++) {
    const int s0 = it * 128;
    __syncthreads();
    #pragma unroll
    for (int j = 0; j < 4; j++) {
      const int c = wid * 4 + j;
      const int row = c * 8 + r8_in;
      const int cb = cb8_ph ^ (row & 7);
      gll16(kh + (size_t)(s0 + row) * DK + cb * 8, &Ks[c * 512]);
    }
    #pragma unroll
    for (int j = 0; j < 4; j++) {
      const int c = wid * 4 + j;
      const int row = c * 4 + r4_in;
      const int cb = cb16_ph ^ (row & 7);
      gll16(vh + (size_t)row * S_LEN + s0 + cb * 8, &Vs[c * 512]);
    }
    __syncthreads();   // vmcnt(0) drain

    floatx4 sc[2][8];
    #pragma unroll
    for (int mt = 0; mt < 2; mt++)
      #pragma unroll
      for (int i = 0; i < 8; i++) sc[mt][i] = (floatx4){0.f, 0.f, 0.f, 0.f};
    #pragma unroll
    for (int kk = 0; kk < 2; kk++) {
      #pragma unroll
      for (int nt = 0; nt < 8; nt++) {
        const int row = nt * 16 + mr;
        const int cb = kk * 4 + q4;
        bf16x8 b = *(const bf16x8*)&Ks[row * 64 + (cb ^ (row & 7)) * 8];
        #pragma unroll
        for (int mt = 0; mt < 2; mt++)
          sc[mt][nt] = __builtin_amdgcn_mfma_f32_16x16x32_bf16(aq[mt][kk], b, sc[mt][nt], 0, 0, 0);
      }
    }

    #pragma unroll
    for (int mt = 0; mt < 2; mt++)
      #pragma unroll
      for (int nt = 0; nt < 8; nt++)
        #pragma unroll
        for (int r = 0; r < 4; r++) {
          const float pv = __expf(sc[mt][nt][r]);
          l_p[mt][r] += pv;
          Ps[wid][mt * 16 + q4 * 4 + r][nt * 16 + mr] = (bf16)pv;
        }

    #pragma unroll
    for (int kk2 = 0; kk2 < 4; kk2++) {
      bf16x8 ap[2];
      #pragma unroll
      for (int mt = 0; mt < 2; mt++)
        ap[mt] = *(const bf16x8*)&Ps[wid][mt * 16 + mr][kk2 * 32 + q4 * 8];
      #pragma unroll
      for (int dt = 0; dt < 4; dt++) {
        const int row = dt * 16 + mr;
        const int cb = kk2 * 4 + q4;
        bf16x8 b = *(const bf16x8*)&Vs[row * 128 + (cb ^ (row & 7)) * 8];
        #pragma unroll
        for (int mt = 0; mt < 2; mt++)
          acc_o[mt][dt] = __builtin_amdgcn_mfma_f32_16x16x32_bf16(ap[mt], b, acc_o[mt][dt], 0, 0, 0);
      }
    }
  }

  const int bi = bh >> 4, h = bh & 15;
  #pragma unroll
  for (int mt = 0; mt < 2; mt++) {
    float inv[4];
    #pragma unroll
    for (int r = 0; r < 4; r++) {
      float v = l_p[mt][r];
      #pragma unroll
      for (int off = 1; off < 16; off <<= 1) v += __shfl_xor(v, off, 16);
      inv[r] = 1.0f / v;
    }
    #pragma unroll
    for (int dt = 0; dt < 4; dt++) {
      const int d = dt * 16 + mr;
      #pragma unroll
      for (int r = 0; r < 4; r++) {
        const int s = qt * 128 + wid * 32 + mt * 16 + q4 * 4 + r;
        ob[((size_t)(bi * S_LEN + s)) * DM + h * DK + d] = (bf16)(acc_o[mt][dt][r] * inv[r]);
      }
    }
  }
}

// ---------------------------------------------------------------------------
// Output projection: out[m,n] = sum_k AO[m,k]*Wo[n,k] + bo[n], fp32 out.
// 128x64 tile, BK=64. XCD-aware: XCD owns 4 m-stripes x all 16 n.
// ---------------------------------------------------------------------------
__global__ __launch_bounds__(256) void oproj_kernel(
    const bf16* __restrict__ X, const float* __restrict__ W,
    const float* __restrict__ bias, float* __restrict__ out)
{
  const int bid = blockIdx.x;
  const int xcd = bid & 7;
  const int slot = bid >> 3;              // 0..63
  const int m0 = (xcd * 4 + (slot & 3)) * 128;
  const int n0 = (slot >> 2) * 64;        // 0..15 -> n0

  const int tid = threadIdx.x;
  const int lane = tid & 63;
  const int wid = tid >> 6;
  const int wm = wid * 32;

  __shared__ bf16  As[128 * 64];   // [row][8 cb]
  __shared__ float Bsf[64 * 64];   // [row][16 cb]

  floatx4 acc[2][4];
  #pragma unroll
  for (int i = 0; i < 2; i++)
    #pragma unroll
    for (int j = 0; j < 4; j++) acc[i][j] = (floatx4){0.f, 0.f, 0.f, 0.f};

  const int mr = lane & 15;
  const int q4 = lane >> 4;

  const int r8_in = lane >> 3, cb8_ph = lane & 7;
  const int r4_in = lane >> 4, cb16_ph = lane & 15;

  for (int kt = 0; kt < DM; kt += 64) {
    __syncthreads();
    #pragma unroll
    for (int j = 0; j < 4; j++) {   // A bf16: 16 chunks (4/wave)
      const int c = wid * 4 + j;
      const int row = c * 8 + r8_in;
      const int cb = cb8_ph ^ (row & 7);
      gll16(X + (size_t)(m0 + row) * DM + kt + cb * 8, &As[c * 512]);
    }
    #pragma unroll
    for (int j = 0; j < 4; j++) {   // B fp32: 16 chunks (4/wave)
      const int c = wid * 4 + j;
      const int row = c * 4 + r4_in;
      const int cb = cb16_ph ^ (row & 7);
      gll16(W + (size_t)(n0 + row) * DM + kt + cb * 4, &Bsf[c * 256]);
    }
    __syncthreads();

    #pragma unroll
    for (int kk = 0; kk < 2; kk++) {
      bf16x8 af[2], bfr[4];
      #pragma unroll
      for (int mt = 0; mt < 2; mt++) {
        const int row = wm + mt * 16 + mr;
        const int cb = 4 * kk + q4;
        af[mt] = *(const bf16x8*)&As[row * 64 + (cb ^ (row & 7)) * 8];
      }
      #pragma unroll
      for (int nt = 0; nt < 4; nt++) {
        const int row = nt * 16 + mr;
        const int cb0 = 8 * kk + 2 * q4;
        const float4 lo = *(const float4*)&Bsf[row * 64 + (cb0 ^ (row & 7)) * 4];
        const float4 hi = *(const float4*)&Bsf[row * 64 + ((cb0 + 1) ^ (row & 7)) * 4];
        bf16x8 b;
        b[0] = (bf16)lo.x; b[1] = (bf16)lo.y; b[2] = (bf16)lo.z; b[3] = (bf16)lo.w;
        b[4] = (bf16)hi.x; b[5] = (bf16)hi.y; b[6] = (bf16)hi.z; b[7] = (bf16)hi.w;
        bfr[nt] = b;
      }
      #pragma unroll
      for (int mt = 0; mt < 2; mt++)
        #pragma unroll
        for (int nt = 0; nt < 4; nt++)
          acc[mt][nt] = __builtin_amdgcn_mfma_f32_16x16x32_bf16(af[mt], bfr[nt], acc[mt][nt], 0, 0, 0);
    }
  }

  #pragma unroll
  for (int nt = 0; nt < 4; nt++) {
    const int gn = n0 + nt * 16 + mr;
    const float bv = bias[gn];
    #pragma unroll
    for (int mt = 0; mt < 2; mt++) {
      const int mbase = m0 + wm + mt * 16 + q4 * 4;
      #pragma unroll
      for (int r = 0; r < 4; r++)
        out[(size_t)(mbase + r) * DM + gn] = acc[mt][nt][r] + bv;
    }
  }
}

// ---------------------------------------------------------------------------
extern "C" void kernel_launch(void* const* d_in, const int* in_sizes, int n_in,
                              void* d_out, int out_size, void* d_ws, size_t ws_size,
                              hipStream_t stream) {
  const float* Q  = (const float*)d_in[0];
  const float* K  = (const float*)d_in[1];
  const float* V  = (const float*)d_in[2];
  const float* Wq = (const float*)d_in[3];
  const float* bq = (const float*)d_in[4];
  const float* Wk = (const float*)d_in[5];
  const float* bk = (const float*)d_in[6];
  const float* Wv = (const float*)d_in[7];
  const float* bv = (const float*)d_in[8];
  const float* Wo = (const float*)d_in[9];
  const float* bo = (const float*)d_in[10];
  float* out = (float*)d_out;

  const size_t NE = (size_t)MTOT * DM;      // 4 Mi elems
  bf16* qb  = (bf16*)d_ws;                  // [B,H,S,Dk] (q pre-scaled by 1/8)
  bf16* kb  = qb + NE;
  bf16* vtb = kb + NE;                      // [B,H,Dk,S]
  bf16* ao  = vtb + NE;                     // [B*S, DM] attn out
  // bf16 weights aliased into ao (live only during proj; attn overwrites ao).
  bf16* wqb = ao;
  bf16* wkb = ao + (size_t)DM * DM;
  bf16* wvb = ao + 2 * (size_t)DM * DM;
  // bf16 Xq/Xk staged in d_out (dead until oproj writes the real output).
  bf16* xqb = (bf16*)d_out;
  bf16* xkb = xqb + NE;

  cvt_kernel<<<dim3(5632), 256, 0, stream>>>(Wq, Wk, Wv, Q, K, wqb, wkb, wvb, xqb, xkb);
  proj_kernel<<<dim3(768), 256, 0, stream>>>(xqb, xkb, V, wqb, wkb, wvb, bq, bk, bv, qb, kb, vtb);
  attn_kernel<<<dim3(512), 256, 0, stream>>>(qb, kb, vtb, ao);
  oproj_kernel<<<dim3(512), 256, 0, stream>>>(ao, Wo, bo, out);
}